// Round 1
// baseline (243.898 us; speedup 1.0000x reference)
//
#include <hip/hip_runtime.h>
#include <math.h>

#define LAM 0.3f
#define EPS 1e-8f

constexpr int B = 32, T = 12, N = 5000, C = 8, E = 5000, M = 160000;
constexpr int F = 16; // 2*C feature dim

// ---------------------------------------------------------------------------
// Kernel 1: per-(b,n) mean/std over T, then normalize the 16-dim vector by
// max(||v||, EPS).  ufeat layout: [B][N][16], contiguous 64B per (b,n).
// ---------------------------------------------------------------------------
__global__ __launch_bounds__(256) void feat_kernel(const float* __restrict__ x,
                                                   float* __restrict__ ufeat) {
    int idx = blockIdx.x * blockDim.x + threadIdx.x; // over B*N
    if (idx >= B * N) return;
    int b = idx / N, n = idx - b * N;
    const float* p = x + ((size_t)b * T * N + n) * C;

    float s[8] = {0, 0, 0, 0, 0, 0, 0, 0};
    float q2[8] = {0, 0, 0, 0, 0, 0, 0, 0};
#pragma unroll
    for (int t = 0; t < T; ++t) {
        const float* pt = p + (size_t)t * N * C;
        float4 a = *(const float4*)(pt);
        float4 bq = *(const float4*)(pt + 4);
        float v[8] = {a.x, a.y, a.z, a.w, bq.x, bq.y, bq.z, bq.w};
#pragma unroll
        for (int c = 0; c < 8; ++c) {
            s[c] += v[c];
            q2[c] += v[c] * v[c];
        }
    }

    float u[16];
    float n2 = 0.0f;
#pragma unroll
    for (int c = 0; c < 8; ++c) {
        float mean = s[c] * (1.0f / T);
        float var = (q2[c] - s[c] * mean) * (1.0f / (T - 1));
        float sd = sqrtf(fmaxf(var, 0.0f));
        u[c] = mean;
        u[8 + c] = sd;
        n2 += mean * mean + sd * sd;
    }
    float scale = 1.0f / fmaxf(sqrtf(n2), EPS);
#pragma unroll
    for (int c = 0; c < 16; ++c) u[c] *= scale;

    float* o = ufeat + (size_t)idx * F;
    *(float4*)(o + 0)  = make_float4(u[0], u[1], u[2], u[3]);
    *(float4*)(o + 4)  = make_float4(u[4], u[5], u[6], u[7]);
    *(float4*)(o + 8)  = make_float4(u[8], u[9], u[10], u[11]);
    *(float4*)(o + 12) = make_float4(u[12], u[13], u[14], u[15]);
}

__device__ __forceinline__ int lower_bound(const int* __restrict__ a, int n, int key) {
    int lo = 0, hi = n;
    while (lo < hi) {
        int mid = (lo + hi) >> 1;
        if (a[mid] < key) lo = mid + 1; else hi = mid;
    }
    return lo;
}

// ---------------------------------------------------------------------------
// Kernel 2: one wave per (b,e).  Segment of sorted member_edge_ids located by
// binary search + counts.  sim = clip(dot(u_member, u_center),0,1); wave
// shuffle-reduce; write mean_sim[b*E+e].  No atomics.
// ---------------------------------------------------------------------------
__global__ __launch_bounds__(256) void sim_kernel(const float* __restrict__ ufeat,
                                                  const int* __restrict__ members,
                                                  const int* __restrict__ centers,
                                                  const int* __restrict__ edge_ids,
                                                  const float* __restrict__ counts,
                                                  float* __restrict__ mean_sim) {
    int wave = blockIdx.x * 4 + (threadIdx.x >> 6);
    int lane = threadIdx.x & 63;
    int b = wave / E, e = wave - b * E;

    int start = lower_bound(edge_ids, M, e);       // wave-uniform
    float cntf = counts[e];
    int cnt = (int)cntf;
    int end = start + cnt;

    const float* cbase = ufeat + ((size_t)b * N + centers[e]) * F;
    float4 c0 = *(const float4*)(cbase + 0);
    float4 c1 = *(const float4*)(cbase + 4);
    float4 c2 = *(const float4*)(cbase + 8);
    float4 c3 = *(const float4*)(cbase + 12);

    float sum = 0.0f;
    for (int i = start + lane; i < end; i += 64) {
        int mi = members[i];
        const float* mbase = ufeat + ((size_t)b * N + mi) * F;
        float4 m0 = *(const float4*)(mbase + 0);
        float4 m1 = *(const float4*)(mbase + 4);
        float4 m2 = *(const float4*)(mbase + 8);
        float4 m3 = *(const float4*)(mbase + 12);
        float d = m0.x * c0.x + m0.y * c0.y + m0.z * c0.z + m0.w * c0.w
                + m1.x * c1.x + m1.y * c1.y + m1.z * c1.z + m1.w * c1.w
                + m2.x * c2.x + m2.y * c2.y + m2.z * c2.z + m2.w * c2.w
                + m3.x * c3.x + m3.y * c3.y + m3.z * c3.z + m3.w * c3.w;
        sum += fminf(fmaxf(d, 0.0f), 1.0f);
    }
#pragma unroll
    for (int off = 32; off > 0; off >>= 1) sum += __shfl_down(sum, off);
    if (lane == 0) mean_sim[wave] = sum / fmaxf(cntf, 1.0f);
}

// ---------------------------------------------------------------------------
// Kernel 3: per-batch min/max over E then write W[e]*(1+LAM*norm).
// One block per b.
// ---------------------------------------------------------------------------
__global__ __launch_bounds__(256) void norm_kernel(const float* __restrict__ mean_sim,
                                                   const float* __restrict__ W,
                                                   float* __restrict__ out) {
    int b = blockIdx.x;
    const float* row = mean_sim + (size_t)b * E;
    float mn = INFINITY, mx = -INFINITY;
    for (int e = threadIdx.x; e < E; e += 256) {
        float v = row[e];
        mn = fminf(mn, v);
        mx = fmaxf(mx, v);
    }
#pragma unroll
    for (int off = 32; off > 0; off >>= 1) {
        mn = fminf(mn, __shfl_down(mn, off));
        mx = fmaxf(mx, __shfl_down(mx, off));
    }
    __shared__ float smn[4], smx[4];
    __shared__ float fmn, fmx;
    int w = threadIdx.x >> 6, lane = threadIdx.x & 63;
    if (lane == 0) { smn[w] = mn; smx[w] = mx; }
    __syncthreads();
    if (threadIdx.x == 0) {
        float a = fminf(fminf(smn[0], smn[1]), fminf(smn[2], smn[3]));
        float c = fmaxf(fmaxf(smx[0], smx[1]), fmaxf(smx[2], smx[3]));
        fmn = a; fmx = c;
    }
    __syncthreads();
    float mnv = fmn;
    float inv = 1.0f / (fmx - mnv + EPS);
    for (int e = threadIdx.x; e < E; e += 256) {
        out[(size_t)b * E + e] = W[e] * (1.0f + LAM * (row[e] - mnv) * inv);
    }
}

extern "C" void kernel_launch(void* const* d_in, const int* in_sizes, int n_in,
                              void* d_out, int out_size, void* d_ws, size_t ws_size,
                              hipStream_t stream) {
    const float* x_raw    = (const float*)d_in[0];
    const float* W        = (const float*)d_in[1];
    const int*   members  = (const int*)d_in[2];
    const int*   centers  = (const int*)d_in[3];
    const int*   edge_ids = (const int*)d_in[4];
    const float* counts   = (const float*)d_in[5];
    float* out = (float*)d_out;

    float* ufeat    = (float*)d_ws;                       // B*N*16 floats = 10.24 MB
    float* mean_sim = ufeat + (size_t)B * N * F;          // B*E floats = 640 KB

    feat_kernel<<<(B * N + 255) / 256, 256, 0, stream>>>(x_raw, ufeat);
    sim_kernel<<<(B * E) / 4, 256, 0, stream>>>(ufeat, members, centers, edge_ids,
                                                counts, mean_sim);
    norm_kernel<<<B, 256, 0, stream>>>(mean_sim, W, out);
}

// Round 2
// 155.132 us; speedup vs baseline: 1.5722x; 1.5722x over previous
//
#include <hip/hip_runtime.h>
#include <math.h>

#define LAM 0.3f
#define EPS 1e-8f

constexpr int B = 32, T = 12, N = 5000, C = 8, E = 5000, M = 160000;
constexpr int F = 16; // 2*C feature dim

// ---------------------------------------------------------------------------
// Kernel 1: per-(b,n) mean/std over T, then normalize the 16-dim vector by
// max(||v||, EPS).  ufeat layout: [B][N][16], contiguous 64B per (b,n).
// ---------------------------------------------------------------------------
__global__ __launch_bounds__(256) void feat_kernel(const float* __restrict__ x,
                                                   float* __restrict__ ufeat) {
    int idx = blockIdx.x * blockDim.x + threadIdx.x; // over B*N
    if (idx >= B * N) return;
    int b = idx / N, n = idx - b * N;
    const float* p = x + ((size_t)b * T * N + n) * C;

    float s[8] = {0, 0, 0, 0, 0, 0, 0, 0};
    float q2[8] = {0, 0, 0, 0, 0, 0, 0, 0};
#pragma unroll
    for (int t = 0; t < T; ++t) {
        const float* pt = p + (size_t)t * N * C;
        float4 a = *(const float4*)(pt);
        float4 bq = *(const float4*)(pt + 4);
        float v[8] = {a.x, a.y, a.z, a.w, bq.x, bq.y, bq.z, bq.w};
#pragma unroll
        for (int c = 0; c < 8; ++c) {
            s[c] += v[c];
            q2[c] += v[c] * v[c];
        }
    }

    float u[16];
    float n2 = 0.0f;
#pragma unroll
    for (int c = 0; c < 8; ++c) {
        float mean = s[c] * (1.0f / T);
        float var = (q2[c] - s[c] * mean) * (1.0f / (T - 1));
        float sd = sqrtf(fmaxf(var, 0.0f));
        u[c] = mean;
        u[8 + c] = sd;
        n2 += mean * mean + sd * sd;
    }
    float scale = 1.0f / fmaxf(sqrtf(n2), EPS);
#pragma unroll
    for (int c = 0; c < 16; ++c) u[c] *= scale;

    float* o = ufeat + (size_t)idx * F;
    *(float4*)(o + 0)  = make_float4(u[0], u[1], u[2], u[3]);
    *(float4*)(o + 4)  = make_float4(u[4], u[5], u[6], u[7]);
    *(float4*)(o + 8)  = make_float4(u[8], u[9], u[10], u[11]);
    *(float4*)(o + 12) = make_float4(u[12], u[13], u[14], u[15]);
}

// ---------------------------------------------------------------------------
// Kernel 1b: exclusive prefix scan of counts -> starts[E].  Single block.
// Replaces 160K per-wave binary searches (18 dependent cache-latency loads
// each) with one ~5us scan.
// ---------------------------------------------------------------------------
__global__ __launch_bounds__(256) void scan_kernel(const float* __restrict__ counts,
                                                   int* __restrict__ starts) {
    constexpr int PER = (E + 255) / 256; // 20
    __shared__ int tsum[256];
    int tid = threadIdx.x;
    int base = tid * PER;
    int local[PER];
    int s = 0;
#pragma unroll
    for (int k = 0; k < PER; ++k) {
        int e = base + k;
        int c = (e < E) ? (int)counts[e] : 0;
        local[k] = s; // exclusive within this thread's chunk
        s += c;
    }
    tsum[tid] = s;
    __syncthreads();
    // Hillis-Steele inclusive scan over the 256 thread sums
    for (int off = 1; off < 256; off <<= 1) {
        int v = (tid >= off) ? tsum[tid - off] : 0;
        __syncthreads();
        tsum[tid] += v;
        __syncthreads();
    }
    int prefix = (tid == 0) ? 0 : tsum[tid - 1];
#pragma unroll
    for (int k = 0; k < PER; ++k) {
        int e = base + k;
        if (e < E) starts[e] = prefix + local[k];
    }
}

// ---------------------------------------------------------------------------
// Kernel 2: 16 lanes per (b,e) (avg segment len = 32, so ~2 packed iters).
// Segment located via precomputed starts[].  sim = clip(dot,0,1);
// 16-wide shuffle reduce; one store per group.  No atomics.
// ---------------------------------------------------------------------------
__global__ __launch_bounds__(256) void sim_kernel(const float* __restrict__ ufeat,
                                                  const int* __restrict__ members,
                                                  const int* __restrict__ centers,
                                                  const int* __restrict__ starts,
                                                  const float* __restrict__ counts,
                                                  float* __restrict__ mean_sim) {
    int group = blockIdx.x * 16 + (threadIdx.x >> 4); // (b,e) index
    int sub = threadIdx.x & 15;
    int b = group / E, e = group - b * E;

    int start = starts[e];
    float cntf = counts[e];
    int end = start + (int)cntf;

    const float* cbase = ufeat + ((size_t)b * N + centers[e]) * F;
    float4 c0 = *(const float4*)(cbase + 0);
    float4 c1 = *(const float4*)(cbase + 4);
    float4 c2 = *(const float4*)(cbase + 8);
    float4 c3 = *(const float4*)(cbase + 12);

    float sum = 0.0f;
    for (int i = start + sub; i < end; i += 16) {
        int mi = members[i];
        const float* mbase = ufeat + ((size_t)b * N + mi) * F;
        float4 m0 = *(const float4*)(mbase + 0);
        float4 m1 = *(const float4*)(mbase + 4);
        float4 m2 = *(const float4*)(mbase + 8);
        float4 m3 = *(const float4*)(mbase + 12);
        float d = m0.x * c0.x + m0.y * c0.y + m0.z * c0.z + m0.w * c0.w
                + m1.x * c1.x + m1.y * c1.y + m1.z * c1.z + m1.w * c1.w
                + m2.x * c2.x + m2.y * c2.y + m2.z * c2.z + m2.w * c2.w
                + m3.x * c3.x + m3.y * c3.y + m3.z * c3.z + m3.w * c3.w;
        sum += fminf(fmaxf(d, 0.0f), 1.0f);
    }
    sum += __shfl_down(sum, 8, 16);
    sum += __shfl_down(sum, 4, 16);
    sum += __shfl_down(sum, 2, 16);
    sum += __shfl_down(sum, 1, 16);
    if (sub == 0) mean_sim[group] = sum / fmaxf(cntf, 1.0f);
}

// ---------------------------------------------------------------------------
// Kernel 3: per-batch min/max over E then write W[e]*(1+LAM*norm).
// One 1024-thread block per b.
// ---------------------------------------------------------------------------
__global__ __launch_bounds__(1024) void norm_kernel(const float* __restrict__ mean_sim,
                                                    const float* __restrict__ W,
                                                    float* __restrict__ out) {
    int b = blockIdx.x;
    const float* row = mean_sim + (size_t)b * E;
    float mn = INFINITY, mx = -INFINITY;
    for (int e = threadIdx.x; e < E; e += 1024) {
        float v = row[e];
        mn = fminf(mn, v);
        mx = fmaxf(mx, v);
    }
#pragma unroll
    for (int off = 32; off > 0; off >>= 1) {
        mn = fminf(mn, __shfl_down(mn, off));
        mx = fmaxf(mx, __shfl_down(mx, off));
    }
    __shared__ float smn[16], smx[16];
    __shared__ float fmn, fmx;
    int w = threadIdx.x >> 6, lane = threadIdx.x & 63;
    if (lane == 0) { smn[w] = mn; smx[w] = mx; }
    __syncthreads();
    if (threadIdx.x == 0) {
        float a = INFINITY, c = -INFINITY;
        for (int i = 0; i < 16; ++i) {
            a = fminf(a, smn[i]);
            c = fmaxf(c, smx[i]);
        }
        fmn = a; fmx = c;
    }
    __syncthreads();
    float mnv = fmn;
    float inv = 1.0f / (fmx - mnv + EPS);
    for (int e = threadIdx.x; e < E; e += 1024) {
        out[(size_t)b * E + e] = W[e] * (1.0f + LAM * (row[e] - mnv) * inv);
    }
}

extern "C" void kernel_launch(void* const* d_in, const int* in_sizes, int n_in,
                              void* d_out, int out_size, void* d_ws, size_t ws_size,
                              hipStream_t stream) {
    const float* x_raw    = (const float*)d_in[0];
    const float* W        = (const float*)d_in[1];
    const int*   members  = (const int*)d_in[2];
    const int*   centers  = (const int*)d_in[3];
    const int*   edge_ids = (const int*)d_in[4]; (void)edge_ids;
    const float* counts   = (const float*)d_in[5];
    float* out = (float*)d_out;

    float* ufeat    = (float*)d_ws;                       // B*N*16 floats = 10.24 MB
    float* mean_sim = ufeat + (size_t)B * N * F;          // B*E floats = 640 KB
    int*   starts   = (int*)(mean_sim + (size_t)B * E);   // E ints

    feat_kernel<<<(B * N + 255) / 256, 256, 0, stream>>>(x_raw, ufeat);
    scan_kernel<<<1, 256, 0, stream>>>(counts, starts);
    sim_kernel<<<(B * E) / 16, 256, 0, stream>>>(ufeat, members, centers, starts,
                                                 counts, mean_sim);
    norm_kernel<<<B, 1024, 0, stream>>>(mean_sim, W, out);
}

// Round 3
// 143.903 us; speedup vs baseline: 1.6949x; 1.0780x over previous
//
#include <hip/hip_runtime.h>
#include <math.h>

#define LAM 0.3f
#define EPS 1e-8f

constexpr int B = 32, T = 12, N = 5000, C = 8, E = 5000, M = 160000;
constexpr int F = 16;       // 2*C feature dim
constexpr int BF = B * F;   // 512 floats = 2KB per node row in [N][B][F]

// ---------------------------------------------------------------------------
// Kernel 1 (fused): blocks 0..624 compute per-(b,n) mean/std over T, normalize
// the 16-dim vector by max(||v||,EPS), and write to ufeat[N][B][F] (64B granule
// scatter).  Block 625 computes the exclusive prefix scan of counts -> starts.
// ---------------------------------------------------------------------------
__global__ __launch_bounds__(256) void feat_scan_kernel(const float* __restrict__ x,
                                                        const float* __restrict__ counts,
                                                        float* __restrict__ ufeat,
                                                        int* __restrict__ starts) {
    if (blockIdx.x == 625) {
        // ---- scan: counts -> starts (exclusive) ----
        constexpr int PER = (E + 255) / 256; // 20
        __shared__ int tsum[256];
        int tid = threadIdx.x;
        int base = tid * PER;
        int local[PER];
        int s = 0;
#pragma unroll
        for (int k = 0; k < PER; ++k) {
            int e = base + k;
            int c = (e < E) ? (int)counts[e] : 0;
            local[k] = s;
            s += c;
        }
        tsum[tid] = s;
        __syncthreads();
        for (int off = 1; off < 256; off <<= 1) {
            int v = (tid >= off) ? tsum[tid - off] : 0;
            __syncthreads();
            tsum[tid] += v;
            __syncthreads();
        }
        int prefix = (tid == 0) ? 0 : tsum[tid - 1];
#pragma unroll
        for (int k = 0; k < PER; ++k) {
            int e = base + k;
            if (e < E) starts[e] = prefix + local[k];
        }
        return;
    }

    // ---- feat: one thread per (b,n) ----
    int idx = blockIdx.x * blockDim.x + threadIdx.x; // exactly covers B*N
    int b = idx / N, n = idx - b * N;
    const float* p = x + ((size_t)b * T * N + n) * C;

    float s[8] = {0, 0, 0, 0, 0, 0, 0, 0};
    float q2[8] = {0, 0, 0, 0, 0, 0, 0, 0};
#pragma unroll
    for (int t = 0; t < T; ++t) {
        const float* pt = p + (size_t)t * N * C;
        float4 a = *(const float4*)(pt);
        float4 bq = *(const float4*)(pt + 4);
        float v[8] = {a.x, a.y, a.z, a.w, bq.x, bq.y, bq.z, bq.w};
#pragma unroll
        for (int c = 0; c < 8; ++c) {
            s[c] += v[c];
            q2[c] += v[c] * v[c];
        }
    }

    float u[16];
    float n2 = 0.0f;
#pragma unroll
    for (int c = 0; c < 8; ++c) {
        float mean = s[c] * (1.0f / T);
        float var = (q2[c] - s[c] * mean) * (1.0f / (T - 1));
        float sd = sqrtf(fmaxf(var, 0.0f));
        u[c] = mean;
        u[8 + c] = sd;
        n2 += mean * mean + sd * sd;
    }
    float scale = 1.0f / fmaxf(sqrtf(n2), EPS);
#pragma unroll
    for (int c = 0; c < 16; ++c) u[c] *= scale;

    // write to [N][B][F]: 64B contiguous granule at n*2KB + b*64B
    float* o = ufeat + (size_t)n * BF + (size_t)b * F;
    *(float4*)(o + 0)  = make_float4(u[0], u[1], u[2], u[3]);
    *(float4*)(o + 4)  = make_float4(u[4], u[5], u[6], u[7]);
    *(float4*)(o + 8)  = make_float4(u[8], u[9], u[10], u[11]);
    *(float4*)(o + 12) = make_float4(u[12], u[13], u[14], u[15]);
}

// ---------------------------------------------------------------------------
// Kernel 2: one block (256 threads) per edge e.  All 32 batches computed
// together: a member's features for all b are 2KB contiguous in [N][B][F].
// Thread t: u = t&127 (float4 granule within row: b = u>>2, q = u&3),
// g = t>>7 (member parity).  Center fragment in registers; member indices
// staged in LDS; per member: coalesced 2KB load + 4 FMA + 2 shuffles.
// ---------------------------------------------------------------------------
__global__ __launch_bounds__(256) void sim_kernel(const float* __restrict__ ufeat,
                                                  const int* __restrict__ members,
                                                  const int* __restrict__ centers,
                                                  const int* __restrict__ starts,
                                                  const float* __restrict__ counts,
                                                  float* __restrict__ mean_sim) {
    int e = blockIdx.x;
    int t = threadIdx.x;
    int u = t & 127;
    int g = t >> 7;

    __shared__ int sidx[256];
    __shared__ float accs[256];

    int start = starts[e];
    float cntf = counts[e];
    int cnt = (int)cntf;
    int ce = centers[e];

    const float4 c4 = *(const float4*)(ufeat + (size_t)ce * BF + u * 4);

    float acc = 0.0f;
    for (int base = 0; base < cnt; base += 256) {
        int csize = min(256, cnt - base);
        __syncthreads();
        if (t < csize) sidx[t] = members[start + base + t];
        __syncthreads();
        for (int j = g; j < csize; j += 2) {
            int mi = sidx[j];
            float4 m = *(const float4*)(ufeat + (size_t)mi * BF + u * 4);
            float p = m.x * c4.x + m.y * c4.y + m.z * c4.z + m.w * c4.w;
            p += __shfl_xor(p, 1);
            p += __shfl_xor(p, 2);
            acc += fminf(fmaxf(p, 0.0f), 1.0f);
        }
    }
    accs[t] = acc;
    __syncthreads();
    if (t < 32) {
        float v = accs[t * 4] + accs[t * 4 + 128];
        mean_sim[(size_t)t * E + e] = v / fmaxf(cntf, 1.0f);
    }
}

// ---------------------------------------------------------------------------
// Kernel 3: per-batch min/max over E then write W[e]*(1+LAM*norm).
// One 1024-thread block per b.
// ---------------------------------------------------------------------------
__global__ __launch_bounds__(1024) void norm_kernel(const float* __restrict__ mean_sim,
                                                    const float* __restrict__ W,
                                                    float* __restrict__ out) {
    int b = blockIdx.x;
    const float* row = mean_sim + (size_t)b * E;
    float mn = INFINITY, mx = -INFINITY;
    for (int e = threadIdx.x; e < E; e += 1024) {
        float v = row[e];
        mn = fminf(mn, v);
        mx = fmaxf(mx, v);
    }
#pragma unroll
    for (int off = 32; off > 0; off >>= 1) {
        mn = fminf(mn, __shfl_down(mn, off));
        mx = fmaxf(mx, __shfl_down(mx, off));
    }
    __shared__ float smn[16], smx[16];
    __shared__ float fmn, fmx;
    int w = threadIdx.x >> 6, lane = threadIdx.x & 63;
    if (lane == 0) { smn[w] = mn; smx[w] = mx; }
    __syncthreads();
    if (threadIdx.x == 0) {
        float a = INFINITY, c = -INFINITY;
        for (int i = 0; i < 16; ++i) {
            a = fminf(a, smn[i]);
            c = fmaxf(c, smx[i]);
        }
        fmn = a; fmx = c;
    }
    __syncthreads();
    float mnv = fmn;
    float inv = 1.0f / (fmx - mnv + EPS);
    for (int e = threadIdx.x; e < E; e += 1024) {
        out[(size_t)b * E + e] = W[e] * (1.0f + LAM * (row[e] - mnv) * inv);
    }
}

extern "C" void kernel_launch(void* const* d_in, const int* in_sizes, int n_in,
                              void* d_out, int out_size, void* d_ws, size_t ws_size,
                              hipStream_t stream) {
    const float* x_raw    = (const float*)d_in[0];
    const float* W        = (const float*)d_in[1];
    const int*   members  = (const int*)d_in[2];
    const int*   centers  = (const int*)d_in[3];
    const int*   edge_ids = (const int*)d_in[4]; (void)edge_ids;
    const float* counts   = (const float*)d_in[5];
    float* out = (float*)d_out;

    float* ufeat    = (float*)d_ws;                       // N*B*F floats = 10.24 MB
    float* mean_sim = ufeat + (size_t)N * BF;             // B*E floats = 640 KB
    int*   starts   = (int*)(mean_sim + (size_t)B * E);   // E ints

    feat_scan_kernel<<<626, 256, 0, stream>>>(x_raw, counts, ufeat, starts);
    sim_kernel<<<E, 256, 0, stream>>>(ufeat, members, centers, starts,
                                      counts, mean_sim);
    norm_kernel<<<B, 1024, 0, stream>>>(mean_sim, W, out);
}

// Round 4
// 126.258 us; speedup vs baseline: 1.9317x; 1.1398x over previous
//
#include <hip/hip_runtime.h>
#include <math.h>

#define LAM 0.3f
#define EPS 1e-8f

constexpr int B = 32, T = 12, N = 5000, C = 8, E = 5000, M = 160000;
constexpr int F = 16;        // 2*C feature dim
constexpr int RH = B * F;    // 512 halves = 1KB per node row in [N][B][F] fp16

typedef _Float16 half8 __attribute__((ext_vector_type(8)));

// ---------------------------------------------------------------------------
// Kernel 1 (fused): blocks 0..624 -> 8 nodes x 32 batches each (one (b,n) per
// thread).  mean/std over T, unit-normalize 16-dim vector, convert to fp16,
// transpose through padded LDS, write 8KB contiguous per block (coalesced).
// Block 625 -> exclusive prefix scan of counts -> starts.
// ---------------------------------------------------------------------------
__global__ __launch_bounds__(256) void feat_scan_kernel(const float* __restrict__ x,
                                                        const float* __restrict__ counts,
                                                        _Float16* __restrict__ ufeat,
                                                        int* __restrict__ starts) {
    if (blockIdx.x == 625) {
        constexpr int PER = (E + 255) / 256; // 20
        __shared__ int tsum[256];
        int tid = threadIdx.x;
        int base = tid * PER;
        int local[PER];
        int s = 0;
#pragma unroll
        for (int k = 0; k < PER; ++k) {
            int e = base + k;
            int c = (e < E) ? (int)counts[e] : 0;
            local[k] = s;
            s += c;
        }
        tsum[tid] = s;
        __syncthreads();
        for (int off = 1; off < 256; off <<= 1) {
            int v = (tid >= off) ? tsum[tid - off] : 0;
            __syncthreads();
            tsum[tid] += v;
            __syncthreads();
        }
        int prefix = (tid == 0) ? 0 : tsum[tid - 1];
#pragma unroll
        for (int k = 0; k < PER; ++k) {
            int e = base + k;
            if (e < E) starts[e] = prefix + local[k];
        }
        return;
    }

    // ---- feat: 625 blocks x (8 nodes, 32 batches) ----
    int tid = threadIdx.x;
    int nb = blockIdx.x * 8;   // node base (625*8 = 5000 exact)
    int nl = tid & 7;          // node local
    int b  = tid >> 3;         // batch 0..31
    int n  = nb + nl;

    const float* p = x + ((size_t)b * T * N + n) * C;

    float s[8] = {0, 0, 0, 0, 0, 0, 0, 0};
    float q2[8] = {0, 0, 0, 0, 0, 0, 0, 0};
#pragma unroll
    for (int t = 0; t < T; ++t) {
        const float* pt = p + (size_t)t * N * C;
        float4 a = *(const float4*)(pt);
        float4 bq = *(const float4*)(pt + 4);
        float v[8] = {a.x, a.y, a.z, a.w, bq.x, bq.y, bq.z, bq.w};
#pragma unroll
        for (int c = 0; c < 8; ++c) {
            s[c] += v[c];
            q2[c] += v[c] * v[c];
        }
    }

    float u[16];
    float n2 = 0.0f;
#pragma unroll
    for (int c = 0; c < 8; ++c) {
        float mean = s[c] * (1.0f / T);
        float var = (q2[c] - s[c] * mean) * (1.0f / (T - 1));
        float sd = sqrtf(fmaxf(var, 0.0f));
        u[c] = mean;
        u[8 + c] = sd;
        n2 += mean * mean + sd * sd;
    }
    float scale = 1.0f / fmaxf(sqrtf(n2), EPS);

    // LDS transpose: [node][b*16+f] halves, row padded +8 halves to spread banks
    __shared__ _Float16 sfeat[8][RH + 8];
    half8 h0, h1;
#pragma unroll
    for (int c = 0; c < 8; ++c) h0[c] = (_Float16)(u[c] * scale);
#pragma unroll
    for (int c = 0; c < 8; ++c) h1[c] = (_Float16)(u[8 + c] * scale);
    *(half8*)&sfeat[nl][b * F + 0] = h0;
    *(half8*)&sfeat[nl][b * F + 8] = h1;
    __syncthreads();

    // coalesced write-out: 8 rows x 1KB = 8KB contiguous; 2 sweeps x 4KB
#pragma unroll
    for (int sw = 0; sw < 2; ++sw) {
        int g = sw * 256 + tid;     // 16B granule id, 0..511
        int nr = g >> 6;            // row (64 granules of 8 halves per 1KB row)
        int off = g & 63;
        half8 v = *(const half8*)&sfeat[nr][off * 8];
        *(half8*)(ufeat + (size_t)(nb + nr) * RH + off * 8) = v;
    }
}

// ---------------------------------------------------------------------------
// Kernel 2: one wave per edge, all 32 batches at once.  Lane u holds the
// center row's 16B granule (b = u>>1, f-half = u&1).  Member indices are
// pre-loaded 64-at-a-time into lane registers and broadcast with __shfl.
// Per member: one coalesced 1KB row read + 8 mixed FMAs + pair shuffle + clip.
// ---------------------------------------------------------------------------
__global__ __launch_bounds__(256) void sim_kernel(const _Float16* __restrict__ ufeat,
                                                  const int* __restrict__ members,
                                                  const int* __restrict__ centers,
                                                  const int* __restrict__ starts,
                                                  const float* __restrict__ counts,
                                                  float* __restrict__ mean_sim) {
    int e = blockIdx.x * 4 + (threadIdx.x >> 6);
    int u = threadIdx.x & 63;

    int start = starts[e];
    float cntf = counts[e];
    int cnt = (int)cntf;
    int ce = centers[e];

    const half8 c8 = *(const half8*)(ufeat + (size_t)ce * RH + u * 8);

    float acc = 0.0f;
    for (int base = 0; base < cnt; base += 64) {
        int chunk = min(64, cnt - base);
        int myidx = (u < chunk) ? members[start + base + u] : 0;
        for (int j = 0; j < chunk; ++j) {
            int mi = __shfl(myidx, j);
            half8 m8 = *(const half8*)(ufeat + (size_t)mi * RH + u * 8);
            float p = 0.0f;
#pragma unroll
            for (int k = 0; k < 8; ++k) p = fmaf((float)m8[k], (float)c8[k], p);
            p += __shfl_xor(p, 1);
            acc += fminf(fmaxf(p, 0.0f), 1.0f);
        }
    }
    if ((u & 1) == 0) {
        mean_sim[(size_t)(u >> 1) * E + e] = acc / fmaxf(cntf, 1.0f);
    }
}

// ---------------------------------------------------------------------------
// Kernel 3: per-batch min/max over E then write W[e]*(1+LAM*norm).
// One 1024-thread block per b.
// ---------------------------------------------------------------------------
__global__ __launch_bounds__(1024) void norm_kernel(const float* __restrict__ mean_sim,
                                                    const float* __restrict__ W,
                                                    float* __restrict__ out) {
    int b = blockIdx.x;
    const float* row = mean_sim + (size_t)b * E;
    float mn = INFINITY, mx = -INFINITY;
    for (int e = threadIdx.x; e < E; e += 1024) {
        float v = row[e];
        mn = fminf(mn, v);
        mx = fmaxf(mx, v);
    }
#pragma unroll
    for (int off = 32; off > 0; off >>= 1) {
        mn = fminf(mn, __shfl_down(mn, off));
        mx = fmaxf(mx, __shfl_down(mx, off));
    }
    __shared__ float smn[16], smx[16];
    __shared__ float fmn, fmx;
    int w = threadIdx.x >> 6, lane = threadIdx.x & 63;
    if (lane == 0) { smn[w] = mn; smx[w] = mx; }
    __syncthreads();
    if (threadIdx.x == 0) {
        float a = INFINITY, c = -INFINITY;
        for (int i = 0; i < 16; ++i) {
            a = fminf(a, smn[i]);
            c = fmaxf(c, smx[i]);
        }
        fmn = a; fmx = c;
    }
    __syncthreads();
    float mnv = fmn;
    float inv = 1.0f / (fmx - mnv + EPS);
    for (int e = threadIdx.x; e < E; e += 1024) {
        out[(size_t)b * E + e] = W[e] * (1.0f + LAM * (row[e] - mnv) * inv);
    }
}

extern "C" void kernel_launch(void* const* d_in, const int* in_sizes, int n_in,
                              void* d_out, int out_size, void* d_ws, size_t ws_size,
                              hipStream_t stream) {
    const float* x_raw    = (const float*)d_in[0];
    const float* W        = (const float*)d_in[1];
    const int*   members  = (const int*)d_in[2];
    const int*   centers  = (const int*)d_in[3];
    const int*   edge_ids = (const int*)d_in[4]; (void)edge_ids;
    const float* counts   = (const float*)d_in[5];
    float* out = (float*)d_out;

    _Float16* ufeat   = (_Float16*)d_ws;                   // N*512 halves = 5.12 MB
    float* mean_sim   = (float*)(ufeat + (size_t)N * RH);  // B*E floats = 640 KB
    int*   starts     = (int*)(mean_sim + (size_t)B * E);  // E ints

    feat_scan_kernel<<<626, 256, 0, stream>>>(x_raw, counts, ufeat, starts);
    sim_kernel<<<E / 4, 256, 0, stream>>>(ufeat, members, centers, starts,
                                          counts, mean_sim);
    norm_kernel<<<B, 1024, 0, stream>>>(mean_sim, W, out);
}

// Round 5
// 125.432 us; speedup vs baseline: 1.9445x; 1.0066x over previous
//
#include <hip/hip_runtime.h>
#include <math.h>

#define LAM 0.3f
#define EPS 1e-8f

constexpr int B = 32, T = 12, N = 5000, C = 8, E = 5000, M = 160000;
constexpr int F = 16;          // 2*C feature dim
constexpr int RH = B * F;      // 512 halves per node across ALL batches
constexpr int HR = 256;        // halves per node per batch-half (16 b x 16 f)
constexpr size_t HN = (size_t)N * HR; // halves per batch-half region

typedef _Float16 half8 __attribute__((ext_vector_type(8)));
typedef _Float16 half2v __attribute__((ext_vector_type(2)));

// ---------------------------------------------------------------------------
// Kernel 1 (fused): blocks 0..624 -> 8 nodes x 32 batches (one (b,n)/thread).
// mean/std over T, unit-normalize, fp16, transpose via padded LDS, write out
// as ufeat[h][n][256] (h = b>>4): 2 x 4KB contiguous coalesced sweeps/block.
// Block 625 -> exclusive prefix scan of counts -> starts.
// ---------------------------------------------------------------------------
__global__ __launch_bounds__(256) void feat_scan_kernel(const float* __restrict__ x,
                                                        const float* __restrict__ counts,
                                                        _Float16* __restrict__ ufeat,
                                                        int* __restrict__ starts) {
    if (blockIdx.x == 625) {
        constexpr int PER = (E + 255) / 256; // 20
        __shared__ int tsum[256];
        int tid = threadIdx.x;
        int base = tid * PER;
        int local[PER];
        int s = 0;
#pragma unroll
        for (int k = 0; k < PER; ++k) {
            int e = base + k;
            int c = (e < E) ? (int)counts[e] : 0;
            local[k] = s;
            s += c;
        }
        tsum[tid] = s;
        __syncthreads();
        for (int off = 1; off < 256; off <<= 1) {
            int v = (tid >= off) ? tsum[tid - off] : 0;
            __syncthreads();
            tsum[tid] += v;
            __syncthreads();
        }
        int prefix = (tid == 0) ? 0 : tsum[tid - 1];
#pragma unroll
        for (int k = 0; k < PER; ++k) {
            int e = base + k;
            if (e < E) starts[e] = prefix + local[k];
        }
        return;
    }

    // ---- feat: 625 blocks x (8 nodes, 32 batches) ----
    int tid = threadIdx.x;
    int nb = blockIdx.x * 8;   // node base (625*8 = 5000 exact)
    int nl = tid & 7;          // node local
    int b  = tid >> 3;         // batch 0..31
    int n  = nb + nl;

    const float* p = x + ((size_t)b * T * N + n) * C;

    float s[8] = {0, 0, 0, 0, 0, 0, 0, 0};
    float q2[8] = {0, 0, 0, 0, 0, 0, 0, 0};
#pragma unroll
    for (int t = 0; t < T; ++t) {
        const float* pt = p + (size_t)t * N * C;
        float4 a = *(const float4*)(pt);
        float4 bq = *(const float4*)(pt + 4);
        float v[8] = {a.x, a.y, a.z, a.w, bq.x, bq.y, bq.z, bq.w};
#pragma unroll
        for (int c = 0; c < 8; ++c) {
            s[c] += v[c];
            q2[c] += v[c] * v[c];
        }
    }

    float u[16];
    float n2 = 0.0f;
#pragma unroll
    for (int c = 0; c < 8; ++c) {
        float mean = s[c] * (1.0f / T);
        float var = (q2[c] - s[c] * mean) * (1.0f / (T - 1));
        float sd = sqrtf(fmaxf(var, 0.0f));
        u[c] = mean;
        u[8 + c] = sd;
        n2 += mean * mean + sd * sd;
    }
    float scale = 1.0f / fmaxf(sqrtf(n2), EPS);

    // LDS transpose: sfeat[node][b*16+f], row padded +8 halves
    __shared__ _Float16 sfeat[8][RH + 8];
    half8 h0, h1;
#pragma unroll
    for (int c = 0; c < 8; ++c) h0[c] = (_Float16)(u[c] * scale);
#pragma unroll
    for (int c = 0; c < 8; ++c) h1[c] = (_Float16)(u[8 + c] * scale);
    *(half8*)&sfeat[nl][b * F + 0] = h0;
    *(half8*)&sfeat[nl][b * F + 8] = h1;
    __syncthreads();

    // coalesced write-out into [h][n][256]: per h, 8 rows x 512B = 4KB contiguous
#pragma unroll
    for (int h = 0; h < 2; ++h) {
        int nr = tid >> 5;           // row 0..7
        int off = tid & 31;          // 16B granule within 512B row
        half8 v = *(const half8*)&sfeat[nr][(h * 16 + (off >> 1)) * F + (off & 1) * 8];
        *(half8*)(ufeat + (size_t)h * HN + (size_t)(nb + nr) * HR + off * 8) = v;
    }
}

// ---------------------------------------------------------------------------
// Kernel 2: grid (E/4, 2).  One wave per (edge, batch-half); per step the two
// half-waves process TWO members (512B row each, 16B/lane dwordx4).  Dot via
// v_dot2_f32_f16 packed fp16 (4 ops), pair shuffle, clip, accumulate; final
// cross-half-wave combine.  Working set per batch-half = 2.56MB (L2-resident).
// ---------------------------------------------------------------------------
__global__ __launch_bounds__(256) void sim_kernel(const _Float16* __restrict__ ufeat,
                                                  const int* __restrict__ members,
                                                  const int* __restrict__ centers,
                                                  const int* __restrict__ starts,
                                                  const float* __restrict__ counts,
                                                  float* __restrict__ mean_sim) {
    int e = blockIdx.x * 4 + (threadIdx.x >> 6);
    int h = blockIdx.y;
    int lane = threadIdx.x & 63;
    int g32 = lane & 31;   // 16B granule within 512B row
    int hw = lane >> 5;    // half-wave id -> member parity

    int start = starts[e];
    float cntf = counts[e];
    int cnt = (int)cntf;
    int ce = centers[e];

    const _Float16* base = ufeat + (size_t)h * HN;
    const half8 c8 = *(const half8*)(base + (size_t)ce * HR + g32 * 8);

    float acc = 0.0f;
    for (int cb = 0; cb < cnt; cb += 64) {
        int chunk = min(64, cnt - cb);
        int myidx = (lane < chunk) ? members[start + cb + lane] : 0;
        for (int j = 0; j < chunk; j += 2) {
            int jj = j + hw;
            int mi = __shfl(myidx, (jj < chunk) ? jj : j);
            half8 m8 = *(const half8*)(base + (size_t)mi * HR + g32 * 8);
            float p = 0.0f;
#if __has_builtin(__builtin_amdgcn_fdot2)
#pragma unroll
            for (int k = 0; k < 4; ++k) {
                half2v a = {m8[2 * k], m8[2 * k + 1]};
                half2v c2 = {c8[2 * k], c8[2 * k + 1]};
                p = __builtin_amdgcn_fdot2(a, c2, p, false);
            }
#else
#pragma unroll
            for (int k = 0; k < 8; ++k) p = fmaf((float)m8[k], (float)c8[k], p);
#endif
            p += __shfl_xor(p, 1);   // combine two 16B granules -> full 16-f dot
            float v = fminf(fmaxf(p, 0.0f), 1.0f);
            acc += (jj < chunk) ? v : 0.0f;
        }
    }
    acc += __shfl_xor(acc, 32);      // combine the two member-parity halves
    if (lane < 32 && (g32 & 1) == 0) {
        int b = h * 16 + (g32 >> 1);
        mean_sim[(size_t)b * E + e] = acc / fmaxf(cntf, 1.0f);
    }
}

// ---------------------------------------------------------------------------
// Kernel 3: per-batch min/max over E then write W[e]*(1+LAM*norm).
// One 1024-thread block per b.
// ---------------------------------------------------------------------------
__global__ __launch_bounds__(1024) void norm_kernel(const float* __restrict__ mean_sim,
                                                    const float* __restrict__ W,
                                                    float* __restrict__ out) {
    int b = blockIdx.x;
    const float* row = mean_sim + (size_t)b * E;
    float mn = INFINITY, mx = -INFINITY;
    for (int e = threadIdx.x; e < E; e += 1024) {
        float v = row[e];
        mn = fminf(mn, v);
        mx = fmaxf(mx, v);
    }
#pragma unroll
    for (int off = 32; off > 0; off >>= 1) {
        mn = fminf(mn, __shfl_down(mn, off));
        mx = fmaxf(mx, __shfl_down(mx, off));
    }
    __shared__ float smn[16], smx[16];
    __shared__ float fmn, fmx;
    int w = threadIdx.x >> 6, lane = threadIdx.x & 63;
    if (lane == 0) { smn[w] = mn; smx[w] = mx; }
    __syncthreads();
    if (threadIdx.x == 0) {
        float a = INFINITY, c = -INFINITY;
        for (int i = 0; i < 16; ++i) {
            a = fminf(a, smn[i]);
            c = fmaxf(c, smx[i]);
        }
        fmn = a; fmx = c;
    }
    __syncthreads();
    float mnv = fmn;
    float inv = 1.0f / (fmx - mnv + EPS);
    for (int e = threadIdx.x; e < E; e += 1024) {
        out[(size_t)b * E + e] = W[e] * (1.0f + LAM * (row[e] - mnv) * inv);
    }
}

extern "C" void kernel_launch(void* const* d_in, const int* in_sizes, int n_in,
                              void* d_out, int out_size, void* d_ws, size_t ws_size,
                              hipStream_t stream) {
    const float* x_raw    = (const float*)d_in[0];
    const float* W        = (const float*)d_in[1];
    const int*   members  = (const int*)d_in[2];
    const int*   centers  = (const int*)d_in[3];
    const int*   edge_ids = (const int*)d_in[4]; (void)edge_ids;
    const float* counts   = (const float*)d_in[5];
    float* out = (float*)d_out;

    _Float16* ufeat   = (_Float16*)d_ws;                    // 2*N*256 halves = 5.12 MB
    float* mean_sim   = (float*)(ufeat + 2 * HN);           // B*E floats = 640 KB
    int*   starts     = (int*)(mean_sim + (size_t)B * E);   // E ints

    feat_scan_kernel<<<626, 256, 0, stream>>>(x_raw, counts, ufeat, starts);
    sim_kernel<<<dim3(E / 4, 2), 256, 0, stream>>>(ufeat, members, centers, starts,
                                                   counts, mean_sim);
    norm_kernel<<<B, 1024, 0, stream>>>(mean_sim, W, out);
}

// Round 6
// 118.116 us; speedup vs baseline: 2.0649x; 1.0619x over previous
//
#include <hip/hip_runtime.h>
#include <math.h>

#define LAM 0.3f
#define EPS 1e-8f

constexpr int B = 32, T = 12, N = 5000, C = 8, E = 5000, M = 160000;
constexpr int F = 16;          // 2*C feature dim
constexpr int RH = B * F;      // 512 halves per node across ALL batches
constexpr int HR = 256;        // halves per node per batch-half (16 b x 16 f)
constexpr size_t HN = (size_t)N * HR; // halves per batch-half region

typedef _Float16 half8 __attribute__((ext_vector_type(8)));
typedef _Float16 half2v __attribute__((ext_vector_type(2)));

__device__ __forceinline__ float dot16(const half8& m, const half8& c, float p0) {
    float p = p0;
#if __has_builtin(__builtin_amdgcn_fdot2)
#pragma unroll
    for (int k = 0; k < 4; ++k) {
        half2v a = {m[2 * k], m[2 * k + 1]};
        half2v c2 = {c[2 * k], c[2 * k + 1]};
        p = __builtin_amdgcn_fdot2(a, c2, p, false);
    }
#else
#pragma unroll
    for (int k = 0; k < 8; ++k) p = fmaf((float)m[k], (float)c[k], p);
#endif
    return p;
}

// ---------------------------------------------------------------------------
// Kernel 1 (fused): blocks 0..624 -> 8 nodes x 32 batches (one (b,n)/thread).
// mean/std over T, unit-normalize, fp16, transpose via padded LDS, write out
// as ufeat[h][n][256] (h = b>>4): 2 x 4KB contiguous coalesced sweeps/block.
// Block 625 -> exclusive prefix scan of counts -> starts.
// ---------------------------------------------------------------------------
__global__ __launch_bounds__(256) void feat_scan_kernel(const float* __restrict__ x,
                                                        const float* __restrict__ counts,
                                                        _Float16* __restrict__ ufeat,
                                                        int* __restrict__ starts) {
    if (blockIdx.x == 625) {
        constexpr int PER = (E + 255) / 256; // 20
        __shared__ int tsum[256];
        int tid = threadIdx.x;
        int base = tid * PER;
        int local[PER];
        int s = 0;
#pragma unroll
        for (int k = 0; k < PER; ++k) {
            int e = base + k;
            int c = (e < E) ? (int)counts[e] : 0;
            local[k] = s;
            s += c;
        }
        tsum[tid] = s;
        __syncthreads();
        for (int off = 1; off < 256; off <<= 1) {
            int v = (tid >= off) ? tsum[tid - off] : 0;
            __syncthreads();
            tsum[tid] += v;
            __syncthreads();
        }
        int prefix = (tid == 0) ? 0 : tsum[tid - 1];
#pragma unroll
        for (int k = 0; k < PER; ++k) {
            int e = base + k;
            if (e < E) starts[e] = prefix + local[k];
        }
        return;
    }

    // ---- feat: 625 blocks x (8 nodes, 32 batches) ----
    int tid = threadIdx.x;
    int nb = blockIdx.x * 8;   // node base (625*8 = 5000 exact)
    int nl = tid & 7;          // node local
    int b  = tid >> 3;         // batch 0..31
    int n  = nb + nl;

    const float* p = x + ((size_t)b * T * N + n) * C;

    float s[8] = {0, 0, 0, 0, 0, 0, 0, 0};
    float q2[8] = {0, 0, 0, 0, 0, 0, 0, 0};
#pragma unroll
    for (int t = 0; t < T; ++t) {
        const float* pt = p + (size_t)t * N * C;
        float4 a = *(const float4*)(pt);
        float4 bq = *(const float4*)(pt + 4);
        float v[8] = {a.x, a.y, a.z, a.w, bq.x, bq.y, bq.z, bq.w};
#pragma unroll
        for (int c = 0; c < 8; ++c) {
            s[c] += v[c];
            q2[c] += v[c] * v[c];
        }
    }

    float u[16];
    float n2 = 0.0f;
#pragma unroll
    for (int c = 0; c < 8; ++c) {
        float mean = s[c] * (1.0f / T);
        float var = (q2[c] - s[c] * mean) * (1.0f / (T - 1));
        float sd = sqrtf(fmaxf(var, 0.0f));
        u[c] = mean;
        u[8 + c] = sd;
        n2 += mean * mean + sd * sd;
    }
    float scale = 1.0f / fmaxf(sqrtf(n2), EPS);

    // LDS transpose: sfeat[node][b*16+f], row padded +8 halves
    __shared__ _Float16 sfeat[8][RH + 8];
    half8 h0, h1;
#pragma unroll
    for (int c = 0; c < 8; ++c) h0[c] = (_Float16)(u[c] * scale);
#pragma unroll
    for (int c = 0; c < 8; ++c) h1[c] = (_Float16)(u[8 + c] * scale);
    *(half8*)&sfeat[nl][b * F + 0] = h0;
    *(half8*)&sfeat[nl][b * F + 8] = h1;
    __syncthreads();

    // coalesced write-out into [h][n][256]: per h, 8 rows x 512B = 4KB contiguous
#pragma unroll
    for (int h = 0; h < 2; ++h) {
        int nr = tid >> 5;           // row 0..7
        int off = tid & 31;          // 16B granule within 512B row
        half8 v = *(const half8*)&sfeat[nr][(h * 16 + (off >> 1)) * F + (off & 1) * 8];
        *(half8*)(ufeat + (size_t)h * HN + (size_t)(nb + nr) * HR + off * 8) = v;
    }
}

// ---------------------------------------------------------------------------
// Kernel 2: one wave per (edge, batch-half).  Block swizzle maps batch-half h
// to XCD group ((linear&7)>>2) so each XCD's L2 serves one 2.56MB half.
// Main loop 4 members/iter: two member rows in flight per wave before either
// is consumed (2x MLP); odd tail handled outside the hot loop.
// ---------------------------------------------------------------------------
__global__ __launch_bounds__(256) void sim_kernel(const _Float16* __restrict__ ufeat,
                                                  const int* __restrict__ members,
                                                  const int* __restrict__ centers,
                                                  const int* __restrict__ starts,
                                                  const float* __restrict__ counts,
                                                  float* __restrict__ mean_sim) {
    int linear = blockIdx.x;                     // 0..2511 (padded)
    int h = (linear & 4) >> 2;                   // XCDs 0-3 -> h=0, 4-7 -> h=1
    int e4 = (linear >> 3) * 4 + (linear & 3);   // edge-quad 0..1255
    if (e4 >= E / 4) return;
    int e = e4 * 4 + (threadIdx.x >> 6);
    int lane = threadIdx.x & 63;
    int g32 = lane & 31;   // 16B granule within 512B row
    int hw = lane >> 5;    // half-wave id -> member parity

    int start = starts[e];
    float cntf = counts[e];
    int cnt = (int)cntf;
    int ce = centers[e];

    const _Float16* base = ufeat + (size_t)h * HN;
    const half8 c8 = *(const half8*)(base + (size_t)ce * HR + g32 * 8);

    float acc = 0.0f;
    for (int cb = 0; cb < cnt; cb += 64) {
        int chunk = min(64, cnt - cb);
        int myidx = (lane < chunk) ? members[start + cb + lane] : 0;
        int jmax4 = chunk & ~3;
        for (int j = 0; j < jmax4; j += 4) {
            int mia = __shfl(myidx, j + hw);
            int mib = __shfl(myidx, j + 2 + hw);
            half8 ma = *(const half8*)(base + (size_t)mia * HR + g32 * 8);
            half8 mb = *(const half8*)(base + (size_t)mib * HR + g32 * 8);
            float pa = dot16(ma, c8, 0.0f);
            float pb = dot16(mb, c8, 0.0f);
            pa += __shfl_xor(pa, 1);
            pb += __shfl_xor(pb, 1);
            acc += fminf(fmaxf(pa, 0.0f), 1.0f) + fminf(fmaxf(pb, 0.0f), 1.0f);
        }
        for (int j = jmax4; j < chunk; j += 2) {
            int jj = j + hw;
            int mi = __shfl(myidx, (jj < chunk) ? jj : j);
            half8 m8 = *(const half8*)(base + (size_t)mi * HR + g32 * 8);
            float p = dot16(m8, c8, 0.0f);
            p += __shfl_xor(p, 1);
            float v = fminf(fmaxf(p, 0.0f), 1.0f);
            acc += (jj < chunk) ? v : 0.0f;
        }
    }
    acc += __shfl_xor(acc, 32);      // combine the two member-parity halves
    if (lane < 32 && (g32 & 1) == 0) {
        int b = h * 16 + (g32 >> 1);
        mean_sim[(size_t)b * E + e] = acc / fmaxf(cntf, 1.0f);
    }
}

// ---------------------------------------------------------------------------
// Kernel 3: per-batch min/max over E then write W[e]*(1+LAM*norm).
// One 1024-thread block per b.
// ---------------------------------------------------------------------------
__global__ __launch_bounds__(1024) void norm_kernel(const float* __restrict__ mean_sim,
                                                    const float* __restrict__ W,
                                                    float* __restrict__ out) {
    int b = blockIdx.x;
    const float* row = mean_sim + (size_t)b * E;
    float mn = INFINITY, mx = -INFINITY;
    for (int e = threadIdx.x; e < E; e += 1024) {
        float v = row[e];
        mn = fminf(mn, v);
        mx = fmaxf(mx, v);
    }
#pragma unroll
    for (int off = 32; off > 0; off >>= 1) {
        mn = fminf(mn, __shfl_down(mn, off));
        mx = fmaxf(mx, __shfl_down(mx, off));
    }
    __shared__ float smn[16], smx[16];
    __shared__ float fmn, fmx;
    int w = threadIdx.x >> 6, lane = threadIdx.x & 63;
    if (lane == 0) { smn[w] = mn; smx[w] = mx; }
    __syncthreads();
    if (threadIdx.x == 0) {
        float a = INFINITY, c = -INFINITY;
        for (int i = 0; i < 16; ++i) {
            a = fminf(a, smn[i]);
            c = fmaxf(c, smx[i]);
        }
        fmn = a; fmx = c;
    }
    __syncthreads();
    float mnv = fmn;
    float inv = 1.0f / (fmx - mnv + EPS);
    for (int e = threadIdx.x; e < E; e += 1024) {
        out[(size_t)b * E + e] = W[e] * (1.0f + LAM * (row[e] - mnv) * inv);
    }
}

extern "C" void kernel_launch(void* const* d_in, const int* in_sizes, int n_in,
                              void* d_out, int out_size, void* d_ws, size_t ws_size,
                              hipStream_t stream) {
    const float* x_raw    = (const float*)d_in[0];
    const float* W        = (const float*)d_in[1];
    const int*   members  = (const int*)d_in[2];
    const int*   centers  = (const int*)d_in[3];
    const int*   edge_ids = (const int*)d_in[4]; (void)edge_ids;
    const float* counts   = (const float*)d_in[5];
    float* out = (float*)d_out;

    _Float16* ufeat   = (_Float16*)d_ws;                    // 2*N*256 halves = 5.12 MB
    float* mean_sim   = (float*)(ufeat + 2 * HN);           // B*E floats = 640 KB
    int*   starts     = (int*)(mean_sim + (size_t)B * E);   // E ints

    feat_scan_kernel<<<626, 256, 0, stream>>>(x_raw, counts, ufeat, starts);
    // 2512 = 314 groups of 8 blocks (4 x h=0, 4 x h=1); e4 padded, checked in-kernel
    sim_kernel<<<2512, 256, 0, stream>>>(ufeat, members, centers, starts,
                                         counts, mean_sim);
    norm_kernel<<<B, 1024, 0, stream>>>(mean_sim, W, out);
}

// Round 9
// 116.856 us; speedup vs baseline: 2.0872x; 1.0108x over previous
//
#include <hip/hip_runtime.h>
#include <math.h>

#define LAM 0.3f
#define EPS 1e-8f

constexpr int B = 32, T = 12, N = 5000, C = 8, E = 5000, M = 160000;
constexpr int F = 16;          // 2*C feature dim
constexpr int RH = B * F;      // 512 halves per node across ALL batches
constexpr int HR = 256;        // halves per node per batch-half (16 b x 16 f)
constexpr size_t HN = (size_t)N * HR; // halves per batch-half region

typedef _Float16 half8 __attribute__((ext_vector_type(8)));
typedef _Float16 half2v __attribute__((ext_vector_type(2)));

__device__ __forceinline__ float dot16(const half8& m, const half8& c, float p0) {
    float p = p0;
#if __has_builtin(__builtin_amdgcn_fdot2)
#pragma unroll
    for (int k = 0; k < 4; ++k) {
        half2v a = {m[2 * k], m[2 * k + 1]};
        half2v c2 = {c[2 * k], c[2 * k + 1]};
        p = __builtin_amdgcn_fdot2(a, c2, p, false);
    }
#else
#pragma unroll
    for (int k = 0; k < 8; ++k) p = fmaf((float)m[k], (float)c[k], p);
#endif
    return p;
}

__device__ __forceinline__ float clip01(float p) {
    return fminf(fmaxf(p, 0.0f), 1.0f);
}

// ---------------------------------------------------------------------------
// Kernel 1 (fused): blocks 0..624 -> 8 nodes x 32 batches (one (b,n)/thread).
// mean/std over T, unit-normalize, fp16, transpose via padded LDS, write out
// as ufeat[h][n][256] (h = b>>4): 2 x 4KB contiguous coalesced sweeps/block.
// Block 625 -> exclusive prefix scan of counts -> starts.
// ---------------------------------------------------------------------------
__global__ __launch_bounds__(256) void feat_scan_kernel(const float* __restrict__ x,
                                                        const float* __restrict__ counts,
                                                        _Float16* __restrict__ ufeat,
                                                        int* __restrict__ starts) {
    if (blockIdx.x == 625) {
        constexpr int PER = (E + 255) / 256; // 20
        __shared__ int tsum[256];
        int tid = threadIdx.x;
        int base = tid * PER;
        int local[PER];
        int s = 0;
#pragma unroll
        for (int k = 0; k < PER; ++k) {
            int e = base + k;
            int c = (e < E) ? (int)counts[e] : 0;
            local[k] = s;
            s += c;
        }
        tsum[tid] = s;
        __syncthreads();
        for (int off = 1; off < 256; off <<= 1) {
            int v = (tid >= off) ? tsum[tid - off] : 0;
            __syncthreads();
            tsum[tid] += v;
            __syncthreads();
        }
        int prefix = (tid == 0) ? 0 : tsum[tid - 1];
#pragma unroll
        for (int k = 0; k < PER; ++k) {
            int e = base + k;
            if (e < E) starts[e] = prefix + local[k];
        }
        return;
    }

    // ---- feat: 625 blocks x (8 nodes, 32 batches) ----
    int tid = threadIdx.x;
    int nb = blockIdx.x * 8;   // node base (625*8 = 5000 exact)
    int nl = tid & 7;          // node local
    int b  = tid >> 3;         // batch 0..31
    int n  = nb + nl;

    const float* p = x + ((size_t)b * T * N + n) * C;

    float s[8] = {0, 0, 0, 0, 0, 0, 0, 0};
    float q2[8] = {0, 0, 0, 0, 0, 0, 0, 0};
#pragma unroll
    for (int t = 0; t < T; ++t) {
        const float* pt = p + (size_t)t * N * C;
        float4 a = *(const float4*)(pt);
        float4 bq = *(const float4*)(pt + 4);
        float v[8] = {a.x, a.y, a.z, a.w, bq.x, bq.y, bq.z, bq.w};
#pragma unroll
        for (int c = 0; c < 8; ++c) {
            s[c] += v[c];
            q2[c] += v[c] * v[c];
        }
    }

    float u[16];
    float n2 = 0.0f;
#pragma unroll
    for (int c = 0; c < 8; ++c) {
        float mean = s[c] * (1.0f / T);
        float var = (q2[c] - s[c] * mean) * (1.0f / (T - 1));
        float sd = sqrtf(fmaxf(var, 0.0f));
        u[c] = mean;
        u[8 + c] = sd;
        n2 += mean * mean + sd * sd;
    }
    float scale = 1.0f / fmaxf(sqrtf(n2), EPS);

    // LDS transpose: sfeat[node][b*16+f], row padded +8 halves
    __shared__ _Float16 sfeat[8][RH + 8];
    half8 h0, h1;
#pragma unroll
    for (int c = 0; c < 8; ++c) h0[c] = (_Float16)(u[c] * scale);
#pragma unroll
    for (int c = 0; c < 8; ++c) h1[c] = (_Float16)(u[8 + c] * scale);
    *(half8*)&sfeat[nl][b * F + 0] = h0;
    *(half8*)&sfeat[nl][b * F + 8] = h1;
    __syncthreads();

    // coalesced write-out into [h][n][256]: per h, 8 rows x 512B = 4KB contiguous
#pragma unroll
    for (int h = 0; h < 2; ++h) {
        int nr = tid >> 5;           // row 0..7
        int off = tid & 31;          // 16B granule within 512B row
        half8 v = *(const half8*)&sfeat[nr][(h * 16 + (off >> 1)) * F + (off & 1) * 8];
        *(half8*)(ufeat + (size_t)h * HN + (size_t)(nb + nr) * HR + off * 8) = v;
    }
}

// ---------------------------------------------------------------------------
// Kernel 2: one wave per (edge, batch-half).  Block swizzle maps batch-half h
// to XCD group so each XCD's L2 serves one 2.56MB half.
// Main loop: 8 members/iter with WAVE-UNIFORM bounds (jmax8 = chunk & ~7) ->
// 4 member-row loads in flight per half-wave; predicated pair-tail identical
// to R5.  NOTE: per-half-wave divergent loop bounds (R6/R7's nh-loop) fail
// reproducibly on HW (absmax 3.1e-2) -- keep ALL loop bounds wave-uniform.
// Fused norm (ticket/fence) also failed (R6); norm stays a separate kernel.
// ---------------------------------------------------------------------------
__global__ __launch_bounds__(256) void sim_kernel(const _Float16* __restrict__ ufeat,
                                                  const int* __restrict__ members,
                                                  const int* __restrict__ centers,
                                                  const int* __restrict__ starts,
                                                  const float* __restrict__ counts,
                                                  float* __restrict__ mean_sim) {
    int linear = blockIdx.x;                     // 0..2511 (padded)
    int h = (linear & 4) >> 2;                   // XCDs 0-3 -> h=0, 4-7 -> h=1
    int e4 = (linear >> 3) * 4 + (linear & 3);   // edge-quad 0..1255 (padded)
    if (e4 >= E / 4) return;
    int e = e4 * 4 + (threadIdx.x >> 6);
    int lane = threadIdx.x & 63;
    int g32 = lane & 31;   // 16B granule within 512B row
    int hw = lane >> 5;    // half-wave id -> member parity

    int start = starts[e];
    float cntf = counts[e];
    int cnt = (int)cntf;
    int ce = centers[e];

    const _Float16* base = ufeat + (size_t)h * HN;
    const half8 c8 = *(const half8*)(base + (size_t)ce * HR + g32 * 8);

    float acc = 0.0f;
    for (int cb = 0; cb < cnt; cb += 64) {
        int chunk = min(64, cnt - cb);
        int myidx = (lane < chunk) ? members[start + cb + lane] : 0;
        int jmax8 = chunk & ~7;              // wave-uniform
        int j = 0;
        for (; j < jmax8; j += 8) {          // 4 loads in flight per half-wave
            int m0 = __shfl(myidx, j + 0 + hw);
            int m1 = __shfl(myidx, j + 2 + hw);
            int m2 = __shfl(myidx, j + 4 + hw);
            int m3 = __shfl(myidx, j + 6 + hw);
            half8 a0 = *(const half8*)(base + (size_t)m0 * HR + g32 * 8);
            half8 a1 = *(const half8*)(base + (size_t)m1 * HR + g32 * 8);
            half8 a2 = *(const half8*)(base + (size_t)m2 * HR + g32 * 8);
            half8 a3 = *(const half8*)(base + (size_t)m3 * HR + g32 * 8);
            float p0 = dot16(a0, c8, 0.0f);
            float p1 = dot16(a1, c8, 0.0f);
            float p2 = dot16(a2, c8, 0.0f);
            float p3 = dot16(a3, c8, 0.0f);
            p0 += __shfl_xor(p0, 1);
            p1 += __shfl_xor(p1, 1);
            p2 += __shfl_xor(p2, 1);
            p3 += __shfl_xor(p3, 1);
            acc += clip01(p0) + clip01(p1) + clip01(p2) + clip01(p3);
        }
        for (; j < chunk; j += 2) {          // predicated pair-tail (R5-exact)
            int jj = j + hw;
            int mi = __shfl(myidx, (jj < chunk) ? jj : j);
            half8 m8 = *(const half8*)(base + (size_t)mi * HR + g32 * 8);
            float p = dot16(m8, c8, 0.0f);
            p += __shfl_xor(p, 1);
            float v = clip01(p);
            acc += (jj < chunk) ? v : 0.0f;
        }
    }
    acc += __shfl_xor(acc, 32);      // combine the two member-parity halves
    if (lane < 32 && (g32 & 1) == 0) {
        int b = h * 16 + (g32 >> 1);
        mean_sim[(size_t)b * E + e] = acc / fmaxf(cntf, 1.0f);
    }
}

// ---------------------------------------------------------------------------
// Kernel 3: per-batch min/max over E then write W[e]*(1+LAM*norm).
// One 1024-thread block per b.
// ---------------------------------------------------------------------------
__global__ __launch_bounds__(1024) void norm_kernel(const float* __restrict__ mean_sim,
                                                    const float* __restrict__ W,
                                                    float* __restrict__ out) {
    int b = blockIdx.x;
    const float* row = mean_sim + (size_t)b * E;
    float mn = INFINITY, mx = -INFINITY;
    for (int e = threadIdx.x; e < E; e += 1024) {
        float v = row[e];
        mn = fminf(mn, v);
        mx = fmaxf(mx, v);
    }
#pragma unroll
    for (int off = 32; off > 0; off >>= 1) {
        mn = fminf(mn, __shfl_down(mn, off));
        mx = fmaxf(mx, __shfl_down(mx, off));
    }
    __shared__ float smn[16], smx[16];
    __shared__ float fmn, fmx;
    int w = threadIdx.x >> 6, lane = threadIdx.x & 63;
    if (lane == 0) { smn[w] = mn; smx[w] = mx; }
    __syncthreads();
    if (threadIdx.x == 0) {
        float a = INFINITY, c = -INFINITY;
        for (int i = 0; i < 16; ++i) {
            a = fminf(a, smn[i]);
            c = fmaxf(c, smx[i]);
        }
        fmn = a; fmx = c;
    }
    __syncthreads();
    float mnv = fmn;
    float inv = 1.0f / (fmx - mnv + EPS);
    for (int e = threadIdx.x; e < E; e += 1024) {
        out[(size_t)b * E + e] = W[e] * (1.0f + LAM * (row[e] - mnv) * inv);
    }
}

extern "C" void kernel_launch(void* const* d_in, const int* in_sizes, int n_in,
                              void* d_out, int out_size, void* d_ws, size_t ws_size,
                              hipStream_t stream) {
    const float* x_raw    = (const float*)d_in[0];
    const float* W        = (const float*)d_in[1];
    const int*   members  = (const int*)d_in[2];
    const int*   centers  = (const int*)d_in[3];
    const int*   edge_ids = (const int*)d_in[4]; (void)edge_ids;
    const float* counts   = (const float*)d_in[5];
    float* out = (float*)d_out;

    _Float16* ufeat   = (_Float16*)d_ws;                    // 2*N*256 halves = 5.12 MB
    float* mean_sim   = (float*)(ufeat + 2 * HN);           // B*E floats = 640 KB
    int*   starts     = (int*)(mean_sim + (size_t)B * E);   // E ints

    feat_scan_kernel<<<626, 256, 0, stream>>>(x_raw, counts, ufeat, starts);
    // 2512 = 314 groups of 8 blocks (4 x h=0, 4 x h=1); e4 padded, checked in-kernel
    sim_kernel<<<2512, 256, 0, stream>>>(ufeat, members, centers, starts,
                                         counts, mean_sim);
    norm_kernel<<<B, 1024, 0, stream>>>(mean_sim, W, out);
}